// Round 5
// baseline (401.947 us; speedup 1.0000x reference)
//
#include <hip/hip_runtime.h>
#include <hip/hip_bf16.h>

typedef unsigned short ushort_t;
typedef unsigned int uint_t;

typedef __bf16 bf16x8 __attribute__((ext_vector_type(8)));
typedef float f32x4 __attribute__((ext_vector_type(4)));

__device__ __forceinline__ float bf2f(ushort_t u) {
    return __uint_as_float(((uint_t)u) << 16);
}
__device__ __forceinline__ ushort_t f2bf(float f) {
    uint_t x = __float_as_uint(f);
    uint_t r = (x + 0x7FFFu + ((x >> 16) & 1u)) >> 16;
    return (ushort_t)r;
}
__device__ __forceinline__ float sigmoidf_fast(float x) {
    return 1.0f / (1.0f + __expf(-x));
}

// Geometry constants
#define PP 12544          // pixels per image plane = 112*112 (= 98*128)
#define PLANE 25690112ULL // elements per k-plane of U2t = 8*256*12544

// ---------------------------------------------------------------------------
// Kernel 1: permute+transpose W2 (fp32 256x768) -> W2t (bf16 768x256).
// n' = k*256 + ch (ch = dir*128+d)  <-  old col = dir*384 + d*3 + k.
// (verbatim round-1 PASSING kernel)
// ---------------------------------------------------------------------------
__global__ __launch_bounds__(256) void permute_w2(const float* __restrict__ W2,
                                                  ushort_t* __restrict__ W2t) {
    int i = blockIdx.x * 256 + threadIdx.x;   // 768*256 total
    int np = i >> 8;        // n' in [0,768)
    int k  = i & 255;       // k  in [0,256)
    int kk  = np >> 8;      // 0..2
    int rem = np & 255;
    int dir = rem >> 7;
    int d   = rem & 127;
    int oc = dir * 384 + d * 3 + kk;
    W2t[np * 256 + k] = f2bf(W2[k * 768 + oc]);
}

// ---------------------------------------------------------------------------
// Kernel 2: fused patch-extract + GEMM1 (K=12, register weights) + SRU scan
// over Wp. Block = (hp,b), thread = channel (dir,d).
// Round-1 PASSING kernel except the store writes H1a[b][p][ch], p=hp*112+wp.
// ---------------------------------------------------------------------------
__global__ __launch_bounds__(256) void scan1(const float* __restrict__ x,
                                             const float* __restrict__ W1,
                                             const float* __restrict__ wc1,
                                             const float* __restrict__ b1,
                                             ushort_t* __restrict__ H1a) {
    __shared__ float patch[112 * 12];
    const int n1 = blockIdx.x;
    const int hp = n1 >> 3, b = n1 & 7;
    const int tid = threadIdx.x;

    for (int e = tid; e < 1344; e += 256) {
        int c = e / 448;
        int rem = e % 448;
        int wh = rem / 224;
        int pos = rem % 224;            // 2*wp + ww
        float v = x[((b * 3 + c) * 224 + (2 * hp + wh)) * 224 + pos];
        patch[(pos >> 1) * 12 + c * 4 + wh * 2 + (pos & 1)] = v;
    }

    float4 w[12];
    const float4* W1v = (const float4*)W1;
#pragma unroll
    for (int j = 0; j < 12; ++j) w[j] = W1v[j * 256 + tid];

    const float vf = wc1[tid],       vr = wc1[256 + tid];
    const float bfv = b1[tid],       brv = b1[256 + tid];
    const int dir = tid >> 7;

    __syncthreads();

    float cst = 0.0f;
    for (int t = 0; t < 112; ++t) {
        const int tt = dir ? (111 - t) : t;
        const float4* pp = (const float4*)(patch + tt * 12);
        float4 p0 = pp[0], p1 = pp[1], p2 = pp[2];
        float pj[12] = {p0.x, p0.y, p0.z, p0.w, p1.x, p1.y, p1.z, p1.w,
                        p2.x, p2.y, p2.z, p2.w};
        float u0 = 0.f, u1 = 0.f, u2 = 0.f, u3 = 0.f;
#pragma unroll
        for (int j = 0; j < 12; ++j) {
            float pv = pj[j];
            u0 = fmaf(w[j].x, pv, u0);
            u1 = fmaf(w[j].y, pv, u1);
            u2 = fmaf(w[j].z, pv, u2);
            u3 = fmaf(w[j].w, pv, u3);
        }
        float f = sigmoidf_fast(u1 + vf * cst + bfv);
        cst = f * cst + (1.0f - f) * u0;
        float r = sigmoidf_fast(u2 + vr * cst + brv);
        float h = r * cst + (1.0f - r) * u3;
        H1a[((size_t)b * PP + hp * 112 + tt) * 256 + tid] = f2bf(h);
    }
}

// ---------------------------------------------------------------------------
// Kernel 3: xp plane: U2t plane3[b][ch][p] = sqrt(2)*H1a[b][p][ch].
// 64x64 LDS transpose, scalar 2B accesses, stride 66 (conflict-free),
// both global phases 128B-contiguous per wave.
// ---------------------------------------------------------------------------
__global__ __launch_bounds__(256) void xp_plane(const ushort_t* __restrict__ H1a,
                                                ushort_t* __restrict__ U2t) {
    __shared__ ushort_t tile[64 * 66];  // 8448 B
    const int pt = blockIdx.x;          // 0..195  (p0 = pt*64)
    const int ct = blockIdx.y;          // 0..3    (ch0 = ct*64)
    const int b  = blockIdx.z;
    const int p0 = pt * 64, ch0 = ct * 64;
    const int tid = threadIdx.x;
    const float SCALE_X = 1.41421356237309515f;

#pragma unroll
    for (int rep = 0; rep < 16; ++rep) {
        int idx = rep * 256 + tid;      // [0,4096)
        int pl = idx >> 6;              // p-local
        int cl = idx & 63;              // ch-local (fast -> coalesced read)
        float v = bf2f(H1a[((size_t)b * PP + p0 + pl) * 256 + ch0 + cl]);
        tile[pl * 66 + cl] = f2bf(v * SCALE_X);
    }
    __syncthreads();
#pragma unroll
    for (int rep = 0; rep < 16; ++rep) {
        int idx = rep * 256 + tid;      // [0,4096)
        int cl = idx >> 6;              // ch-local
        int pl = idx & 63;              // p-local (fast -> coalesced write)
        U2t[3 * PLANE + ((size_t)b * 256 + ch0 + cl) * PP + p0 + pl] =
            tile[pl * 66 + cl];
    }
}

// ---------------------------------------------------------------------------
// Kernel 4: bf16 MFMA GEMM: H1a(M x 256) @ W2t^T, M=100352 (m = b*PP+p).
// K-loop/staging verbatim round-1 PASSING. Epilogue: per-lane aligned
// ushort4 stores into U2t k-plane [k][b][ch][p].
// ---------------------------------------------------------------------------
__global__ __launch_bounds__(256) void gemm2(const ushort_t* __restrict__ A,
                                             const ushort_t* __restrict__ Bt,
                                             ushort_t* __restrict__ U2t) {
    __shared__ ushort_t As[128 * 32];   // [row][k] 64B rows
    __shared__ ushort_t Bs[128 * 32];   // [n][k]   64B rows
    const int m0 = blockIdx.y * 128;
    const int bb = blockIdx.y / 98;        // batch index (m0 == bb*PP + p0)
    const int p0 = (blockIdx.y % 98) * 128;
    const int n0 = blockIdx.x * 128;
    const int kidx = n0 >> 8;              // 0..2
    const int ch0  = n0 & 255;             // 0 or 128
    const int tid = threadIdx.x;
    const int w = tid >> 6, lane = tid & 63;
    const int wm = w >> 1, wn = w & 1;
    const int lr = lane >> 2;
    const int lc = (lane & 3) * 8;
    const int ln16 = lane & 15;
    const int k8 = (lane >> 4) * 8;

    f32x4 acc[4][4] = {};

    for (int kb = 0; kb < 256; kb += 32) {
        if (kb) __syncthreads();
#pragma unroll
        for (int q = 0; q < 2; ++q) {
            int r = w * 32 + q * 16;
            const ushort_t* gA = A + (size_t)(m0 + r + lr) * 256 + kb + lc;
            __builtin_amdgcn_global_load_lds(
                (const __attribute__((address_space(1))) uint_t*)gA,
                (__attribute__((address_space(3))) uint_t*)(As + r * 32), 16, 0, 0);
            const ushort_t* gB = Bt + (size_t)(n0 + r + lr) * 256 + kb + lc;
            __builtin_amdgcn_global_load_lds(
                (const __attribute__((address_space(1))) uint_t*)gB,
                (__attribute__((address_space(3))) uint_t*)(Bs + r * 32), 16, 0, 0);
        }
        __syncthreads();

        bf16x8 af[4], bf[4];
#pragma unroll
        for (int i = 0; i < 4; ++i) {
            af[i] = *(const bf16x8*)(As + (wm * 64 + i * 16 + ln16) * 32 + k8);
            bf[i] = *(const bf16x8*)(Bs + (wn * 64 + i * 16 + ln16) * 32 + k8);
        }
#pragma unroll
        for (int i = 0; i < 4; ++i)
#pragma unroll
            for (int j = 0; j < 4; ++j)
                acc[i][j] = __builtin_amdgcn_mfma_f32_16x16x32_bf16(
                    af[i], bf[j], acc[i][j], 0, 0, 0);
    }

    // Epilogue: C/D layout col(N)=lane&15, row(M)=(lane>>4)*4+reg.
    // Lane owns 4 consecutive p at fixed ch -> one aligned 8B store.
    const int rq = (lane >> 4) * 4;
    const size_t planeBase = (size_t)kidx * PLANE + (size_t)(bb * 256 + ch0) * PP;
#pragma unroll
    for (int i = 0; i < 4; ++i) {
        int p = p0 + wm * 64 + i * 16 + rq;
#pragma unroll
        for (int j = 0; j < 4; ++j) {
            int ch_l = wn * 64 + j * 16 + ln16;
            ushort4 v;
            v.x = f2bf(acc[i][j][0]);
            v.y = f2bf(acc[i][j][1]);
            v.z = f2bf(acc[i][j][2]);
            v.w = f2bf(acc[i][j][3]);
            *(ushort4*)(U2t + planeBase + (size_t)ch_l * PP + p) = v;
        }
    }
}

// ---------------------------------------------------------------------------
// Kernel 5: SRU scan over hp, writes d_out directly (b,ch,hp,wp).
// 256 threads = 2 ch x 128 lanes (wp>=112 idle), wave-uniform dir,
// grid (128,8) = 1024 blocks. Depth-1 prefetch.
// FIX vs r2-r4: ostep is +-112 (hp stride in out), NOT +-12544.
// ---------------------------------------------------------------------------
__global__ __launch_bounds__(256) void scan2(const ushort_t* __restrict__ U2t,
                                             const float* __restrict__ wc2,
                                             const float* __restrict__ b2,
                                             float* __restrict__ out) {
    const int cb = blockIdx.x;             // 0..127
    const int b  = blockIdx.y;             // 0..7
    const int tid = threadIdx.x;
    const int ch = cb * 2 + (tid >> 7);    // 0..255
    const int wp = tid & 127;
    if (wp >= 112) return;
    const int dir = ch >> 7;

    const float vf = wc2[ch],  vr = wc2[256 + ch];
    const float bfv = b2[ch],  brv = b2[256 + ch];

    const int tt0 = dir ? 111 : 0;
    const long dstep = dir ? -112 : 112;   // hp stride in U2t planes (p = hp*112+wp)
    const long ostep = dir ? -112 : 112;   // hp stride in out  (FIXED: was +-12544)

    long off  = (long)((size_t)(b * 256 + ch) * PP) + tt0 * 112 + wp;
    long oOff = (long)((size_t)(b * 256 + ch) * 112 + tt0) * 112 + wp;

    const ushort_t* P = U2t;
    ushort_t a0 = P[off];
    ushort_t a1 = P[PLANE + off];
    ushort_t a2 = P[2 * PLANE + off];
    ushort_t a3 = P[3 * PLANE + off];

    float cst = 0.0f;
    for (int t = 0; t < 112; ++t) {
        long noff = off + ((t < 111) ? dstep : 0);
        ushort_t n0 = P[noff];
        ushort_t n1 = P[PLANE + noff];
        ushort_t n2 = P[2 * PLANE + noff];
        ushort_t n3 = P[3 * PLANE + noff];

        float u0 = bf2f(a0), u1 = bf2f(a1), u2v = bf2f(a2);
        float xp = bf2f(a3);               // already scaled by sqrt(2)
        float f = sigmoidf_fast(u1 + vf * cst + bfv);
        cst = f * cst + (1.0f - f) * u0;
        float r = sigmoidf_fast(u2v + vr * cst + brv);
        out[oOff] = r * cst + (1.0f - r) * xp;

        a0 = n0; a1 = n1; a2 = n2; a3 = n3;
        off = noff;
        oOff += ostep;
    }
}

// ---------------------------------------------------------------------------
// Launch. Workspace layout (bytes):
//   H1a bf16 [b][p][ch] 8*12544*256       @ 0          (51,380,224)
//   U2t bf16 4 planes [k][b][ch][p]       @ 51380224   (205,520,896)
//   W2t bf16 768*256                      @ 256901120  (393,216)
//   total 257,294,336 B  (round 1 proved >= 308 MB available)
// ---------------------------------------------------------------------------
extern "C" void kernel_launch(void* const* d_in, const int* in_sizes, int n_in,
                              void* d_out, int out_size, void* d_ws, size_t ws_size,
                              hipStream_t stream) {
    const float* x   = (const float*)d_in[0];
    const float* W1  = (const float*)d_in[1];
    const float* wc1 = (const float*)d_in[2];
    const float* b1  = (const float*)d_in[3];
    const float* W2  = (const float*)d_in[4];
    const float* wc2 = (const float*)d_in[5];
    const float* b2  = (const float*)d_in[6];
    float* out = (float*)d_out;

    char* ws = (char*)d_ws;
    ushort_t* H1a = (ushort_t*)(ws);
    ushort_t* U2t = (ushort_t*)(ws + 51380224);
    ushort_t* W2t = (ushort_t*)(ws + 51380224 + 205520896);

    permute_w2<<<768, 256, 0, stream>>>(W2, W2t);
    scan1<<<896, 256, 0, stream>>>(x, W1, wc1, b1, H1a);
    xp_plane<<<dim3(196, 4, 8), 256, 0, stream>>>(H1a, U2t);
    gemm2<<<dim3(6, 784), 256, 0, stream>>>(H1a, W2t, U2t);
    scan2<<<dim3(128, 8), 256, 0, stream>>>(U2t, wc2, b2, out);
}

// Round 6
// 380.373 us; speedup vs baseline: 1.0567x; 1.0567x over previous
//
#include <hip/hip_runtime.h>
#include <hip/hip_bf16.h>

typedef unsigned short ushort_t;
typedef unsigned int uint_t;

typedef __bf16 bf16x8 __attribute__((ext_vector_type(8)));
typedef float f32x4 __attribute__((ext_vector_type(4)));

__device__ __forceinline__ float bf2f(ushort_t u) {
    return __uint_as_float(((uint_t)u) << 16);
}
__device__ __forceinline__ ushort_t f2bf(float f) {
    uint_t x = __float_as_uint(f);
    uint_t r = (x + 0x7FFFu + ((x >> 16) & 1u)) >> 16;
    return (ushort_t)r;
}
__device__ __forceinline__ float sigmoidf_fast(float x) {
    return 1.0f / (1.0f + __expf(-x));
}

// Geometry constants
#define PP 12544          // pixels per image plane = 112*112 (= 98*128)
#define PLANE 25690112ULL // elements per k-plane of U2t = 8*256*12544

// ---------------------------------------------------------------------------
// Kernel 1: permute+transpose W2 (fp32 256x768) -> W2t (bf16 768x256).
// (verbatim verified)
// ---------------------------------------------------------------------------
__global__ __launch_bounds__(256) void permute_w2(const float* __restrict__ W2,
                                                  ushort_t* __restrict__ W2t) {
    int i = blockIdx.x * 256 + threadIdx.x;   // 768*256 total
    int np = i >> 8;        // n' in [0,768)
    int k  = i & 255;       // k  in [0,256)
    int kk  = np >> 8;      // 0..2
    int rem = np & 255;
    int dir = rem >> 7;
    int d   = rem & 127;
    int oc = dir * 384 + d * 3 + kk;
    W2t[np * 256 + k] = f2bf(W2[k * 768 + oc]);
}

// ---------------------------------------------------------------------------
// Kernel 2: fused patch-extract + GEMM1 (K=12, register weights) + SRU scan
// over Wp. Block = (hp,b), thread = channel (dir,d). Writes:
//   H1a[b][p][ch] (bf16, GEMM A operand), p = hp*112+wp
//   U2t plane3[b][ch][p] = sqrt(2)*h (scan2's xprime), via hbuf LDS transpose
//   (hbuf stride 258: both phases consecutive-address -> conflict-free).
// ---------------------------------------------------------------------------
__global__ __launch_bounds__(256) void scan1(const float* __restrict__ x,
                                             const float* __restrict__ W1,
                                             const float* __restrict__ wc1,
                                             const float* __restrict__ b1,
                                             ushort_t* __restrict__ H1a,
                                             ushort_t* __restrict__ U2t) {
    __shared__ float patch[112 * 12];       // 5376 B
    __shared__ ushort_t hbuf[112 * 258];    // 57792 B (total 63168 B < 64 KB)
    const int n1 = blockIdx.x;
    const int hp = n1 >> 3, b = n1 & 7;
    const int tid = threadIdx.x;
    const float SCALE_X = 1.41421356237309515f;

    for (int e = tid; e < 1344; e += 256) {
        int c = e / 448;
        int rem = e % 448;
        int wh = rem / 224;
        int pos = rem % 224;            // 2*wp + ww
        float v = x[((b * 3 + c) * 224 + (2 * hp + wh)) * 224 + pos];
        patch[(pos >> 1) * 12 + c * 4 + wh * 2 + (pos & 1)] = v;
    }

    float4 w[12];
    const float4* W1v = (const float4*)W1;
#pragma unroll
    for (int j = 0; j < 12; ++j) w[j] = W1v[j * 256 + tid];

    const float vf = wc1[tid],       vr = wc1[256 + tid];
    const float bfv = b1[tid],       brv = b1[256 + tid];
    const int dir = tid >> 7;

    __syncthreads();

    float cst = 0.0f;
    for (int t = 0; t < 112; ++t) {
        const int tt = dir ? (111 - t) : t;
        const float4* pp = (const float4*)(patch + tt * 12);
        float4 p0 = pp[0], p1 = pp[1], p2 = pp[2];
        float pj[12] = {p0.x, p0.y, p0.z, p0.w, p1.x, p1.y, p1.z, p1.w,
                        p2.x, p2.y, p2.z, p2.w};
        float u0 = 0.f, u1 = 0.f, u2 = 0.f, u3 = 0.f;
#pragma unroll
        for (int j = 0; j < 12; ++j) {
            float pv = pj[j];
            u0 = fmaf(w[j].x, pv, u0);
            u1 = fmaf(w[j].y, pv, u1);
            u2 = fmaf(w[j].z, pv, u2);
            u3 = fmaf(w[j].w, pv, u3);
        }
        float f = sigmoidf_fast(u1 + vf * cst + bfv);
        cst = f * cst + (1.0f - f) * u0;
        float r = sigmoidf_fast(u2 + vr * cst + brv);
        float h = r * cst + (1.0f - r) * u3;
        H1a[((size_t)b * PP + hp * 112 + tt) * 256 + tid] = f2bf(h);
        hbuf[tt * 258 + tid] = f2bf(h * SCALE_X);
    }

    __syncthreads();
    // Plane-3 write-out: U2t[3][b][ch][hp*112+wp] = hbuf[wp][ch], wp-coalesced.
    const size_t base3 = 3 * PLANE + (size_t)b * 256 * PP + (size_t)hp * 112;
    for (int e = tid; e < 28672; e += 256) {
        int ch = e / 112;
        int wp = e - ch * 112;
        U2t[base3 + (size_t)ch * PP + wp] = hbuf[wp * 258 + ch];
    }
}

// ---------------------------------------------------------------------------
// Kernel 3: bf16 MFMA GEMM: H1a(M x 256) @ W2t^T, M=100352 (m = b*PP+p).
// 128x128 tile. K-unroll x2: two BK=32 sub-tiles staged per barrier pair
// (identical per-sub-tile layout to the verified r5 kernel; barriers 8 -> 4).
// Epilogue: per-lane aligned ushort4 stores into U2t k-plane [k][b][ch][p].
// ---------------------------------------------------------------------------
__global__ __launch_bounds__(256) void gemm2(const ushort_t* __restrict__ A,
                                             const ushort_t* __restrict__ Bt,
                                             ushort_t* __restrict__ U2t) {
    __shared__ ushort_t As[2][128 * 32];   // [half][row][k] 64B rows, 8 KB each
    __shared__ ushort_t Bs[2][128 * 32];   // total 32 KB
    const int m0 = blockIdx.y * 128;
    const int bb = blockIdx.y / 98;        // batch index (m0 == bb*PP + p0)
    const int p0 = (blockIdx.y % 98) * 128;
    const int n0 = blockIdx.x * 128;
    const int kidx = n0 >> 8;              // 0..2
    const int ch0  = n0 & 255;             // 0 or 128
    const int tid = threadIdx.x;
    const int w = tid >> 6, lane = tid & 63;
    const int wm = w >> 1, wn = w & 1;
    const int lr = lane >> 2;
    const int lc = (lane & 3) * 8;
    const int ln16 = lane & 15;
    const int k8 = (lane >> 4) * 8;

    f32x4 acc[4][4] = {};

    for (int kb = 0; kb < 256; kb += 64) {
        if (kb) __syncthreads();
#pragma unroll
        for (int h = 0; h < 2; ++h) {
#pragma unroll
            for (int q = 0; q < 2; ++q) {
                int r = w * 32 + q * 16;   // wave-uniform base row of 1KB chunk
                const ushort_t* gA = A + (size_t)(m0 + r + lr) * 256 + kb + h * 32 + lc;
                __builtin_amdgcn_global_load_lds(
                    (const __attribute__((address_space(1))) uint_t*)gA,
                    (__attribute__((address_space(3))) uint_t*)(As[h] + r * 32), 16, 0, 0);
                const ushort_t* gB = Bt + (size_t)(n0 + r + lr) * 256 + kb + h * 32 + lc;
                __builtin_amdgcn_global_load_lds(
                    (const __attribute__((address_space(1))) uint_t*)gB,
                    (__attribute__((address_space(3))) uint_t*)(Bs[h] + r * 32), 16, 0, 0);
            }
        }
        __syncthreads();

#pragma unroll
        for (int h = 0; h < 2; ++h) {
            bf16x8 af[4], bf[4];
#pragma unroll
            for (int i = 0; i < 4; ++i) {
                af[i] = *(const bf16x8*)(As[h] + (wm * 64 + i * 16 + ln16) * 32 + k8);
                bf[i] = *(const bf16x8*)(Bs[h] + (wn * 64 + i * 16 + ln16) * 32 + k8);
            }
#pragma unroll
            for (int i = 0; i < 4; ++i)
#pragma unroll
                for (int j = 0; j < 4; ++j)
                    acc[i][j] = __builtin_amdgcn_mfma_f32_16x16x32_bf16(
                        af[i], bf[j], acc[i][j], 0, 0, 0);
        }
    }

    // Epilogue: C/D layout col(N)=lane&15, row(M)=(lane>>4)*4+reg.
    const int rq = (lane >> 4) * 4;
    const size_t planeBase = (size_t)kidx * PLANE + (size_t)(bb * 256 + ch0) * PP;
#pragma unroll
    for (int i = 0; i < 4; ++i) {
        int p = p0 + wm * 64 + i * 16 + rq;
#pragma unroll
        for (int j = 0; j < 4; ++j) {
            int ch_l = wn * 64 + j * 16 + ln16;
            ushort4 v;
            v.x = f2bf(acc[i][j][0]);
            v.y = f2bf(acc[i][j][1]);
            v.z = f2bf(acc[i][j][2]);
            v.w = f2bf(acc[i][j][3]);
            *(ushort4*)(U2t + planeBase + (size_t)ch_l * PP + p) = v;
        }
    }
}

// ---------------------------------------------------------------------------
// Kernel 4: SRU scan over hp, writes d_out directly (b,ch,hp,wp).
// 256 threads = 2 ch x 128 lanes (wp>=112 idle), wave-uniform dir,
// grid (128,8) = 1024 blocks. Depth-3 shift-register prefetch: loads for
// t+3 issue while computing t -> ~3 iterations of latency slack.
// ---------------------------------------------------------------------------
__global__ __launch_bounds__(256) void scan2(const ushort_t* __restrict__ U2t,
                                             const float* __restrict__ wc2,
                                             const float* __restrict__ b2,
                                             float* __restrict__ out) {
    const int cb = blockIdx.x;             // 0..127
    const int b  = blockIdx.y;             // 0..7
    const int tid = threadIdx.x;
    const int ch = cb * 2 + (tid >> 7);    // 0..255
    const int wp = tid & 127;
    if (wp >= 112) return;
    const int dir = ch >> 7;

    const float vf = wc2[ch],  vr = wc2[256 + ch];
    const float bfv = b2[ch],  brv = b2[256 + ch];

    const int tt0 = dir ? 111 : 0;
    const long dstep = dir ? -112 : 112;   // hp stride in U2t planes
    const long ostep = dir ? -112 : 112;   // hp stride in out

    const ushort_t* P = U2t;
    long q    = (long)((size_t)(b * 256 + ch) * PP) + tt0 * 112 + wp;
    long oOff = (long)((size_t)(b * 256 + ch) * 112 + tt0) * 112 + wp;

    // Preload t=0,1,2 (x=t, y=t+1, z=t+2); q ends pointing at t+2.
    ushort_t x0 = P[q], x1 = P[PLANE + q], x2 = P[2 * PLANE + q], x3 = P[3 * PLANE + q];
    q += dstep;
    ushort_t y0 = P[q], y1 = P[PLANE + q], y2 = P[2 * PLANE + q], y3 = P[3 * PLANE + q];
    q += dstep;
    ushort_t z0 = P[q], z1 = P[PLANE + q], z2 = P[2 * PLANE + q], z3 = P[3 * PLANE + q];

    float cst = 0.0f;
    for (int t = 0; t < 112; ++t) {
        // issue loads for t+3 (clamped to t=111's address when past the end)
        long qn = q + ((t < 109) ? dstep : 0);
        ushort_t w0 = P[qn], w1 = P[PLANE + qn], w2 = P[2 * PLANE + qn], w3 = P[3 * PLANE + qn];

        float u0 = bf2f(x0), u1 = bf2f(x1), u2v = bf2f(x2);
        float xp = bf2f(x3);               // already scaled by sqrt(2)
        float f = sigmoidf_fast(u1 + vf * cst + bfv);
        cst = f * cst + (1.0f - f) * u0;
        float r = sigmoidf_fast(u2v + vr * cst + brv);
        out[oOff] = r * cst + (1.0f - r) * xp;

        x0 = y0; x1 = y1; x2 = y2; x3 = y3;
        y0 = z0; y1 = z1; y2 = z2; y3 = z3;
        z0 = w0; z1 = w1; z2 = w2; z3 = w3;
        q = qn;
        oOff += ostep;
    }
}

// ---------------------------------------------------------------------------
// Launch. Workspace layout (bytes):
//   H1a bf16 [b][p][ch] 8*12544*256       @ 0          (51,380,224)
//   U2t bf16 4 planes [k][b][ch][p]       @ 51380224   (205,520,896)
//   W2t bf16 768*256                      @ 256901120  (393,216)
// ---------------------------------------------------------------------------
extern "C" void kernel_launch(void* const* d_in, const int* in_sizes, int n_in,
                              void* d_out, int out_size, void* d_ws, size_t ws_size,
                              hipStream_t stream) {
    const float* x   = (const float*)d_in[0];
    const float* W1  = (const float*)d_in[1];
    const float* wc1 = (const float*)d_in[2];
    const float* b1  = (const float*)d_in[3];
    const float* W2  = (const float*)d_in[4];
    const float* wc2 = (const float*)d_in[5];
    const float* b2  = (const float*)d_in[6];
    float* out = (float*)d_out;

    char* ws = (char*)d_ws;
    ushort_t* H1a = (ushort_t*)(ws);
    ushort_t* U2t = (ushort_t*)(ws + 51380224);
    ushort_t* W2t = (ushort_t*)(ws + 51380224 + 205520896);

    permute_w2<<<768, 256, 0, stream>>>(W2, W2t);
    scan1<<<896, 256, 0, stream>>>(x, W1, wc1, b1, H1a, U2t);
    gemm2<<<dim3(6, 784), 256, 0, stream>>>(H1a, W2t, U2t);
    scan2<<<dim3(128, 8), 256, 0, stream>>>(U2t, wc2, b2, out);
}